// Round 1
// baseline (15048.758 us; speedup 1.0000x reference)
//
#include <hip/hip_runtime.h>
#include <math.h>

#define B_  256
#define T_  512
#define D_  256
#define H_  1024
#define O_  128
#define K_  (H_ + D_)     // 1280
#define N4H 4096          // 4*H

typedef __attribute__((ext_vector_type(8))) short bf16x8;
typedef __attribute__((ext_vector_type(4))) float f32x4;

__device__ __forceinline__ unsigned short f2bf(float x) {
    union { float f; unsigned u; } v; v.f = x;
    unsigned r = v.u + 0x7fffu + ((v.u >> 16) & 1u);
    return (unsigned short)(r >> 16);
}
__device__ __forceinline__ float bf2f(unsigned short b) {
    union { float f; unsigned u; } v; v.u = ((unsigned)b) << 16;
    return v.f;
}

// ---------------------------------------------------------------------------
// Pack weights: rows n' = 4*j + gate (gate: 0=g,1=i,2=f,3=o), cols k:
//   k <  H : Wh[gate][j][k]   (recurrent part)
//   k >= H : Wx[gate][j][k-H] (input part)
// split into hi/lo bf16. Also pack bias (x-side bias only, as in reference).
// ---------------------------------------------------------------------------
__global__ __launch_bounds__(256) void pack_weights(
    const float* __restrict__ Wgx, const float* __restrict__ bgx, const float* __restrict__ Wgh,
    const float* __restrict__ Wix, const float* __restrict__ bix, const float* __restrict__ Wih,
    const float* __restrict__ Wfx, const float* __restrict__ bfx, const float* __restrict__ Wfh,
    const float* __restrict__ Wox, const float* __restrict__ box, const float* __restrict__ Woh,
    unsigned short* __restrict__ Whi, unsigned short* __restrict__ Wlo,
    float* __restrict__ biasP)
{
    int idx = blockIdx.x * 256 + threadIdx.x;
    const int total = N4H * K_;
    if (idx < total) {
        int np = idx / K_;
        int k  = idx - np * K_;
        int j = np >> 2, g = np & 3;
        const float* Wh = (g == 0) ? Wgh : (g == 1) ? Wih : (g == 2) ? Wfh : Woh;
        const float* Wx = (g == 0) ? Wgx : (g == 1) ? Wix : (g == 2) ? Wfx : Wox;
        float w = (k < H_) ? Wh[j * H_ + k] : Wx[j * D_ + (k - H_)];
        unsigned short hi = f2bf(w);
        Whi[idx] = hi;
        Wlo[idx] = f2bf(w - bf2f(hi));
    }
    if (idx < N4H) {
        int j = idx >> 2, g = idx & 3;
        const float* bx = (g == 0) ? bgx : (g == 1) ? bix : (g == 2) ? bfx : box;
        biasP[idx] = bx[j];
    }
}

// ---------------------------------------------------------------------------
// One LSTM time step, fused GEMM + cell update.
// Grid: (64 colgroups, 4 rowgroups), 256 threads (4 waves).
// Block tile: 64 batch rows x 64 packed cols (= 16 LSTM cells wide).
// Waves split K (1280 -> 4 x 320) into private accumulators; LDS reduce.
// 3-pass split-bf16 MFMA for ~fp32 accuracy.
// ---------------------------------------------------------------------------
__global__ __launch_bounds__(256, 1) void lstm_step(
    const float* __restrict__ x,
    const unsigned short* __restrict__ Whi, const unsigned short* __restrict__ Wlo,
    const float* __restrict__ biasP,
    const unsigned short* __restrict__ hin_hi, const unsigned short* __restrict__ hin_lo,
    unsigned short* __restrict__ hout_hi, unsigned short* __restrict__ hout_lo,
    float* __restrict__ cst, int t)
{
    __shared__ float zbuf[4][64][68];   // [wave][row][col], padded

    const int tid  = threadIdx.x;
    const int wave = tid >> 6;
    const int lane = tid & 63;
    const int lrow = lane & 15;
    const int quad = lane >> 4;

    const int cg = blockIdx.x;          // column group: cols [cg*64, cg*64+64)
    const int rg = blockIdx.y;          // row group:    rows [rg*64, rg*64+64)
    const int rbase = rg * 64;
    const int cbase = cg * 64;

    f32x4 acc[4][4];
    #pragma unroll
    for (int rs = 0; rs < 4; ++rs)
        #pragma unroll
        for (int cs = 0; cs < 4; ++cs)
            acc[rs][cs] = (f32x4){0.f, 0.f, 0.f, 0.f};

    const int k0 = wave * 320;
    const int k1 = k0 + 320;
    const int kh_end = (k1 < H_) ? k1 : H_;

    // ---- recurrent part: A from pre-split h (bf16 hi/lo) ----
    for (int kc = k0; kc < kh_end; kc += 32) {
        bf16x8 Ahi[4], Alo[4], Bh[4], Bl[4];
        #pragma unroll
        for (int rs = 0; rs < 4; ++rs) {
            int r = rbase + rs * 16 + lrow;
            int off = r * H_ + kc + quad * 8;
            Ahi[rs] = *(const bf16x8*)(hin_hi + off);
            Alo[rs] = *(const bf16x8*)(hin_lo + off);
        }
        #pragma unroll
        for (int cs = 0; cs < 4; ++cs) {
            int rw = cbase + cs * 16 + lrow;
            int off = rw * K_ + kc + quad * 8;
            Bh[cs] = *(const bf16x8*)(Whi + off);
            Bl[cs] = *(const bf16x8*)(Wlo + off);
        }
        #pragma unroll
        for (int rs = 0; rs < 4; ++rs)
            #pragma unroll
            for (int cs = 0; cs < 4; ++cs) {
                acc[rs][cs] = __builtin_amdgcn_mfma_f32_16x16x32_bf16(Ahi[rs], Bh[cs], acc[rs][cs], 0, 0, 0);
                acc[rs][cs] = __builtin_amdgcn_mfma_f32_16x16x32_bf16(Ahi[rs], Bl[cs], acc[rs][cs], 0, 0, 0);
                acc[rs][cs] = __builtin_amdgcn_mfma_f32_16x16x32_bf16(Alo[rs], Bh[cs], acc[rs][cs], 0, 0, 0);
            }
    }

    // ---- input part: A from fp32 x, split on the fly ----
    const int kx_beg = (k0 > H_) ? k0 : H_;
    for (int kc = kx_beg; kc < k1; kc += 32) {
        bf16x8 Ahi[4], Alo[4], Bh[4], Bl[4];
        #pragma unroll
        for (int rs = 0; rs < 4; ++rs) {
            int r = rbase + rs * 16 + lrow;
            const float* p = x + (size_t)r * (T_ * D_) + (size_t)t * D_ + (kc - H_) + quad * 8;
            float4 v0 = *(const float4*)p;
            float4 v1 = *(const float4*)(p + 4);
            float vv[8] = {v0.x, v0.y, v0.z, v0.w, v1.x, v1.y, v1.z, v1.w};
            bf16x8 hi8, lo8;
            #pragma unroll
            for (int j = 0; j < 8; ++j) {
                unsigned short h16 = f2bf(vv[j]);
                hi8[j] = (short)h16;
                lo8[j] = (short)f2bf(vv[j] - bf2f(h16));
            }
            Ahi[rs] = hi8; Alo[rs] = lo8;
        }
        #pragma unroll
        for (int cs = 0; cs < 4; ++cs) {
            int rw = cbase + cs * 16 + lrow;
            int off = rw * K_ + kc + quad * 8;
            Bh[cs] = *(const bf16x8*)(Whi + off);
            Bl[cs] = *(const bf16x8*)(Wlo + off);
        }
        #pragma unroll
        for (int rs = 0; rs < 4; ++rs)
            #pragma unroll
            for (int cs = 0; cs < 4; ++cs) {
                acc[rs][cs] = __builtin_amdgcn_mfma_f32_16x16x32_bf16(Ahi[rs], Bh[cs], acc[rs][cs], 0, 0, 0);
                acc[rs][cs] = __builtin_amdgcn_mfma_f32_16x16x32_bf16(Ahi[rs], Bl[cs], acc[rs][cs], 0, 0, 0);
                acc[rs][cs] = __builtin_amdgcn_mfma_f32_16x16x32_bf16(Alo[rs], Bh[cs], acc[rs][cs], 0, 0, 0);
            }
    }

    // ---- write per-wave partials to LDS ----
    #pragma unroll
    for (int rs = 0; rs < 4; ++rs)
        #pragma unroll
        for (int cs = 0; cs < 4; ++cs)
            #pragma unroll
            for (int r = 0; r < 4; ++r)
                zbuf[wave][rs * 16 + quad * 4 + r][cs * 16 + lrow] = acc[rs][cs][r];
    __syncthreads();

    // ---- epilogue: each thread handles 4 LSTM cells ----
    const int b_loc = tid >> 2;          // 0..63
    const int cq    = tid & 3;           // col quarter (16 packed cols each)

    float zz[16];
    #pragma unroll
    for (int i = 0; i < 16; i += 4) {
        float sx = 0.f, sy = 0.f, sz = 0.f, sw = 0.f;
        #pragma unroll
        for (int w = 0; w < 4; ++w) {
            float4 v = *(const float4*)&zbuf[w][b_loc][cq * 16 + i];
            sx += v.x; sy += v.y; sz += v.z; sw += v.w;
        }
        zz[i] = sx; zz[i + 1] = sy; zz[i + 2] = sz; zz[i + 3] = sw;
    }

    const float* bp = biasP + cbase + cq * 16;
    float bias[16];
    #pragma unroll
    for (int i = 0; i < 16; i += 4) {
        float4 v = *(const float4*)(bp + i);
        bias[i] = v.x; bias[i + 1] = v.y; bias[i + 2] = v.z; bias[i + 3] = v.w;
    }

    const int b   = rbase + b_loc;
    const int jg0 = cg * 16 + cq * 4;    // global cell index of first cell
    float4 cold = *(const float4*)&cst[b * H_ + jg0];
    float coldv[4] = {cold.x, cold.y, cold.z, cold.w};

    float cnew[4];
    unsigned short hh[4], hl[4];
    #pragma unroll
    for (int j = 0; j < 4; ++j) {
        float zg = zz[4 * j + 0] + bias[4 * j + 0];
        float zi = zz[4 * j + 1] + bias[4 * j + 1];
        float zf = zz[4 * j + 2] + bias[4 * j + 2];
        float zo = zz[4 * j + 3] + bias[4 * j + 3];
        float g  = tanhf(zg);
        float ig = 1.f / (1.f + expf(-zi));
        float fg = 1.f / (1.f + expf(-zf));
        float og = 1.f / (1.f + expf(-zo));
        float cn = g * ig + coldv[j] * fg;
        float hn = tanhf(cn) * og;
        cnew[j] = cn;
        unsigned short h16 = f2bf(hn);
        hh[j] = h16;
        hl[j] = f2bf(hn - bf2f(h16));
    }
    *(float4*)&cst[b * H_ + jg0] = make_float4(cnew[0], cnew[1], cnew[2], cnew[3]);
    *(ushort4*)&hout_hi[b * H_ + jg0] = make_ushort4(hh[0], hh[1], hh[2], hh[3]);
    *(ushort4*)&hout_lo[b * H_ + jg0] = make_ushort4(hl[0], hl[1], hl[2], hl[3]);
}

// ---------------------------------------------------------------------------
// Final projection + softmax: one block per batch row, 128 threads (one per
// output class).
// ---------------------------------------------------------------------------
__global__ __launch_bounds__(128) void final_proj(
    const unsigned short* __restrict__ hhi, const unsigned short* __restrict__ hlo,
    const float* __restrict__ Why, const float* __restrict__ bhy,
    float* __restrict__ out)
{
    __shared__ float hsh[H_];
    __shared__ float red[O_];
    const int b = blockIdx.x, tid = threadIdx.x;

    for (int k = tid; k < H_; k += O_)
        hsh[k] = bf2f(hhi[(size_t)b * H_ + k]) + bf2f(hlo[(size_t)b * H_ + k]);
    __syncthreads();

    float s = bhy[tid];
    const float* w = Why + (size_t)tid * H_;
    #pragma unroll 4
    for (int k = 0; k < H_; k += 4) {
        float4 wv = *(const float4*)(w + k);
        s += hsh[k] * wv.x + hsh[k + 1] * wv.y + hsh[k + 2] * wv.z + hsh[k + 3] * wv.w;
    }

    red[tid] = s; __syncthreads();
    for (int off = 64; off > 0; off >>= 1) {
        if (tid < off) red[tid] = fmaxf(red[tid], red[tid + off]);
        __syncthreads();
    }
    float mx = red[0]; __syncthreads();
    float e = expf(s - mx);
    red[tid] = e; __syncthreads();
    for (int off = 64; off > 0; off >>= 1) {
        if (tid < off) red[tid] += red[tid + off];
        __syncthreads();
    }
    out[(size_t)b * O_ + tid] = e / red[0];
}

// ---------------------------------------------------------------------------
extern "C" void kernel_launch(void* const* d_in, const int* in_sizes, int n_in,
                              void* d_out, int out_size, void* d_ws, size_t ws_size,
                              hipStream_t stream)
{
    const float* x   = (const float*)d_in[0];
    const float* Wgx = (const float*)d_in[1];
    const float* bgx = (const float*)d_in[2];
    const float* Wgh = (const float*)d_in[3];
    const float* Wix = (const float*)d_in[4];
    const float* bix = (const float*)d_in[5];
    const float* Wih = (const float*)d_in[6];
    const float* Wfx = (const float*)d_in[7];
    const float* bfx = (const float*)d_in[8];
    const float* Wfh = (const float*)d_in[9];
    const float* Wox = (const float*)d_in[10];
    const float* box = (const float*)d_in[11];
    const float* Woh = (const float*)d_in[12];
    const float* Why = (const float*)d_in[13];
    const float* bhy = (const float*)d_in[14];

    // workspace layout (~24 MB)
    unsigned short* Whi  = (unsigned short*)d_ws;
    unsigned short* Wlo  = Whi + (size_t)N4H * K_;
    float*          bP   = (float*)(Wlo + (size_t)N4H * K_);
    unsigned short* hA_hi = (unsigned short*)(bP + N4H);
    unsigned short* hA_lo = hA_hi + (size_t)B_ * H_;
    float*          cst   = (float*)(hA_lo + (size_t)B_ * H_);
    unsigned short* hB_hi = (unsigned short*)(cst + (size_t)B_ * H_);
    unsigned short* hB_lo = hB_hi + (size_t)B_ * H_;

    // zero h (ping buffer) and c: contiguous region hA_hi, hA_lo, cst
    hipMemsetAsync(hA_hi, 0, (size_t)B_ * H_ * (2 + 2 + 4), stream);

    const int totalW = N4H * K_;
    pack_weights<<<(totalW + 255) / 256, 256, 0, stream>>>(
        Wgx, bgx, Wgh, Wix, bix, Wih, Wfx, bfx, Wfh, Wox, box, Woh,
        Whi, Wlo, bP);

    for (int t = 0; t < T_; ++t) {
        const unsigned short* ih = (t & 1) ? hB_hi : hA_hi;
        const unsigned short* il = (t & 1) ? hB_lo : hA_lo;
        unsigned short* oh = (t & 1) ? hA_hi : hB_hi;
        unsigned short* ol = (t & 1) ? hA_lo : hB_lo;
        lstm_step<<<dim3(64, 4), 256, 0, stream>>>(
            x, Whi, Wlo, bP, ih, il, oh, ol, cst, t);
    }

    // T=512 is even, so last step (t=511, odd) wrote the A buffers
    final_proj<<<B_, 128, 0, stream>>>(hA_hi, hA_lo, Why, bhy, (float*)d_out);
}